// Round 2
// baseline (2588.763 us; speedup 1.0000x reference)
//
#include <hip/hip_runtime.h>
#include <stdint.h>

// Resonator network, b=1024 f=4 v=64 d=2048, 100 iterations.
// All values are +-1 -> pure bit arithmetic (exact vs f32 reference).
// Round 2: 16 waves per row (4-way split of phase B/C per factor) +
// exact limit-cycle detection up to period 7 (hash prefilter + full verify).

#define NB 1024
#define NF 4
#define NV 64
#define ND 2048
#define NW 32            // ND/64 words per row
#define ITERS 100

#define OFF_OUT  (NB*NF*ND)            // outcome
#define OFF_MS   (OFF_OUT + NB*NF)     // max_sims[-1]
#define OFF_CONV (OFF_MS + NB*NF)      // convergence scalar

typedef unsigned long long u64;

__device__ __forceinline__ u64 rotl64v(u64 x, int r) {
    return r ? ((x << r) | (x >> (64 - r))) : x;
}

// Pack codebooks (f,v,d) +-1 floats into two bit layouts in d_ws:
//  cbB[(j*32+w)*64 + v] : row bits, bit l = sign of cb[j,v,w*64+l]
//  cbT[j*2048 + d]      : column mask, bit v = sign of cb[j,v,d]
__global__ void pack_cb_kernel(const float* __restrict__ cb,
                               u64* __restrict__ cbB, u64* __restrict__ cbT) {
    const int lane = threadIdx.x & 63;
    const int gw   = (blockIdx.x * (blockDim.x >> 6)) + (threadIdx.x >> 6);
    const int nw   = (gridDim.x * blockDim.x) >> 6;
    for (int idx = gw; idx < NF * NV * NW; idx += nw) {
        const int j = idx >> 11, v = (idx >> 5) & 63, w = idx & 31;
        const float x = cb[(((j << 6) | v) << 11) + (w << 6) + lane];
        const u64 m = __ballot(x < 0.0f);
        if (lane == 0) cbB[(((j << 5) | w) << 6) | v] = m;
    }
    for (int idx = gw; idx < NF * ND; idx += nw) {
        const int j = idx >> 11, d = idx & 2047;
        const float x = cb[(((j << 6) | lane) << 11) + d];
        const u64 m = __ballot(x < 0.0f);
        if (lane == 0) cbT[idx] = m;
    }
}

// One block per batch row b. 16 waves: wave = (h,j), j=factor, h=quarter of
// the word range. Ring buffer of last 8 states enables exact period<=7 exit.
__global__ __launch_bounds__(1024, 2) void resonator_kernel(
    const float* __restrict__ inp, const float* __restrict__ est_init,
    const u64* __restrict__ cbB, const u64* __restrict__ cbT,
    float* __restrict__ out) {
    __shared__ u64 s_hist[8][NF][NW];   // est_k at slot k%8 (8 KB)
    __shared__ u64 s_inp[NW];
    __shared__ u64 s_X[NW];             // inp ^ est0 ^ est1 ^ est2 ^ est3
    __shared__ int s_pcp[4][NF][NV];    // partial popcounts (4 KB)
    __shared__ u64 s_hpx[16], s_hpa[16];
    __shared__ u64 s_hashx[8], s_hasha[8];
    __shared__ int s_ms[8][NF];         // msim ring
    __shared__ int s_pf, s_vf;

    const int b    = blockIdx.x;
    const int tid  = threadIdx.x;
    const int wid  = tid >> 6;      // 0..15
    const int lane = tid & 63;
    const int j    = wid & 3;       // factor
    const int h    = wid >> 2;      // quarter 0..3

    // ---- pack input + init estimates; hash est_0 ----
    {
        u64 hx = 0, ha = 0;
        #pragma unroll
        for (int k = 0; k < 2; ++k) {
            const int w = (wid << 1) + k;
            const float x = inp[(b << 11) + (w << 6) + lane];
            const u64 m = __ballot(x < 0.0f);
            if (lane == 0) s_inp[w] = m;
        }
        #pragma unroll
        for (int k = 0; k < 8; ++k) {
            const int idx = (wid << 3) + k;        // 0..127
            const int jj = idx >> 5, w = idx & 31;
            const float x = est_init[(((b << 2) | jj) << 11) + (w << 6) + lane];
            const u64 m = __ballot(x < 0.0f);
            if (lane == 0) s_hist[0][jj][w] = m;
            hx ^= rotl64v(m, (w * 11) & 63);
            ha += m;
        }
        if (lane == 0) { s_hpx[wid] = hx; s_hpa[wid] = ha; }
        if (tid == 0) { s_pf = 0; s_vf = 0; }
    }
    __syncthreads();
    if (tid == 0) {        // only tid0 ever reads s_hash*; done before B1 below
        u64 HX = 0, HA = 0;
        for (int q = 0; q < 16; ++q) { HX ^= s_hpx[q]; HA += s_hpa[q]; }
        s_hashx[0] = HX; s_hasha[0] = HA;
    }

    const u64* cbBj = cbB + (j << 11);
    const u64* cbTj = cbT + (j << 11);

    int m_last  = 0;
    int fs      = ITERS & 7;   // default: est_100 at slot 4
    int ms_ring = -1;          // >=0: take max_sim from s_ms[ms_ring][j]

    for (int it = 0; it < ITERS; ++it) {
        const int cur = it & 7;
        const int nxt = (it + 1) & 7;

        if (tid < NW)
            s_X[tid] = s_inp[tid] ^ s_hist[cur][0][tid] ^ s_hist[cur][1][tid]
                                  ^ s_hist[cur][2][tid] ^ s_hist[cur][3][tid];
        __syncthreads();                                   // B1

        // ---- phase B: partial similarity popcounts; lane = v ----
        int pcp = 0;
        #pragma unroll
        for (int k = 0; k < 8; ++k) {
            const int w = (h << 3) + k;
            pcp += (int)__popcll(s_X[w] ^ s_hist[cur][j][w] ^ cbBj[(w << 6) | lane]);
        }
        s_pcp[h][j][lane] = pcp;
        __syncthreads();                                   // B2

        const int pc = s_pcp[0][j][lane] + s_pcp[1][j][lane]
                     + s_pcp[2][j][lane] + s_pcp[3][j][lane];
        const int sim = ND - (pc << 1);
        int msim = sim, spc = pc;
        #pragma unroll
        for (int off = 32; off > 0; off >>= 1) {
            const int t1 = __shfl_xor(msim, off);
            msim = msim > t1 ? msim : t1;
            spc += __shfl_xor(spc, off);
        }
        if (h == 0 && lane == 0) s_ms[cur][j] = msim;
        m_last = msim;

        u64 c[12];
        #pragma unroll
        for (int k = 0; k < 12; ++k) c[k] = __ballot((pc >> k) & 1);

        // ---- phase C: sign of t_d; lane = d%64, words h*8..h*8+7 ----
        const int tbase = 131072 - (spc << 1);
        u64 hx = 0, ha = 0;
        #pragma unroll
        for (int k = 0; k < 8; ++k) {
            const int k2 = (h << 3) + k;
            const u64 col = cbTj[(k2 << 6) | lane];
            int t = tbase - ((int)__popcll(col) << 12);
            #pragma unroll
            for (int kk = 0; kk < 12; ++kk)
                t += (int)__popcll(c[kk] & col) << (kk + 2);
            const u64 nww = __ballot(t < 0);
            if (lane == 0) s_hist[nxt][j][k2] = nww;
            hx ^= rotl64v(nww, (k2 * 11) & 63);
            ha += nww;
        }
        if (lane == 0) { s_hpx[wid] = hx; s_hpa[wid] = ha; }
        __syncthreads();                                   // B3

        // ---- period detection: 128-bit hash ring, exact verify ----
        if (tid == 0) {
            u64 HX = 0, HA = 0;
            for (int q = 0; q < 16; ++q) { HX ^= s_hpx[q]; HA += s_hpa[q]; }
            s_hashx[nxt] = HX; s_hasha[nxt] = HA;
            int mask = 0;
            const int pmax = (it + 1) < 7 ? (it + 1) : 7;
            for (int p = 1; p <= pmax; ++p)
                if (s_hashx[(it + 1 - p) & 7] == HX && s_hasha[(it + 1 - p) & 7] == HA)
                    mask |= (1 << p);
            s_pf = mask;
        }
        __syncthreads();                                   // B4

        const int mask = s_pf;
        if (mask) {
            int period = 0;
            for (int p = 1; p <= 7 && !period; ++p) {
                if (!(mask & (1 << p))) continue;
                if (tid < 128) {
                    const int jj = tid >> 5, w = tid & 31;
                    if (s_hist[nxt][jj][w] != s_hist[(it + 1 - p) & 7][jj][w])
                        atomicOr(&s_vf, 1);
                }
                __syncthreads();
                const int bad = s_vf;
                __syncthreads();
                if (!bad) {
                    period = p;
                } else {
                    if (tid == 0) s_vf = 0;
                    __syncthreads();
                }
            }
            if (period) {
                // orbit = est_{start..it}, est_{n+period} == est_n for n>=start
                const int start = it + 1 - period;
                const int q100  = start + ((ITERS     - start) % period);
                const int q99   = start + ((ITERS - 1 - start) % period);
                fs      = q100 & 7;
                ms_ring = q99 & 7;
                break;
            }
        }
    }
    __syncthreads();

    // ---- outcome: argmax_v |sim(est_final, cb)| (waves h==0 only) ----
    if (h == 0) {
        int pcF = 0;
        #pragma unroll 8
        for (int w = 0; w < NW; ++w)
            pcF += (int)__popcll(s_hist[fs][j][w] ^ cbBj[(w << 6) | lane]);
        const int simF = ND - (pcF << 1);
        const int aF   = simF < 0 ? -simF : simF;
        int key = (aF << 6) | (63 - lane);
        #pragma unroll
        for (int off = 32; off > 0; off >>= 1) {
            const int t1 = __shfl_xor(key, off);
            key = key > t1 ? key : t1;
        }
        const int vstar = 63 - (key & 63);
        const int msv = (ms_ring >= 0) ? s_ms[ms_ring][j] : m_last;
        if (lane == 0) {
            out[OFF_OUT + (b << 2) + j] = (float)vstar;
            out[OFF_MS  + (b << 2) + j] = (float)msv;
        }
    }
    // ---- unpack final estimates ----
    #pragma unroll
    for (int k = 0; k < 8; ++k) {
        const int idx = tid + (k << 10);       // 0..8191
        const int jj = idx >> 11, d = idx & 2047;
        const u64 wrd = s_hist[fs][jj][d >> 6];
        out[(b << 13) + idx] = ((wrd >> (d & 63)) & 1) ? -1.0f : 1.0f;
    }
    if (b == 0 && tid == 0) out[OFF_CONV] = 99.0f;
}

extern "C" void kernel_launch(void* const* d_in, const int* in_sizes, int n_in,
                              void* d_out, int out_size, void* d_ws, size_t ws_size,
                              hipStream_t stream) {
    const float* inp  = (const float*)d_in[0];
    const float* est0 = (const float*)d_in[1];
    const float* cb   = (const float*)d_in[2];
    float* out = (float*)d_out;
    u64* cbB = (u64*)d_ws;                 // 8192 words
    u64* cbT = cbB + NF * NV * NW;         // 8192 words (128 KB of ws total)

    pack_cb_kernel<<<64, 256, 0, stream>>>(cb, cbB, cbT);
    resonator_kernel<<<NB, 1024, 0, stream>>>(inp, est0, cbB, cbT, out);
}

// Round 3
// 2337.072 us; speedup vs baseline: 1.1077x; 1.1077x over previous
//
#include <hip/hip_runtime.h>
#include <stdint.h>

// Resonator network, b=1024 f=4 v=64 d=2048, 100 iterations.
// All values +-1 -> exact bit arithmetic. Round 3: back to 4-wave blocks
// (1 row/block); cbT held in VGPRs; adaptive plane count (min-offset);
// free msim; period<=15 AND anti-period<=15 (effective 30) exact exits.

#define NB 1024
#define NF 4
#define NV 64
#define ND 2048
#define NW 32            // ND/64 words per row
#define ITERS 100
#define RING 16

#define OFF_OUT  (NB*NF*ND)
#define OFF_MS   (OFF_OUT + NB*NF)
#define OFF_CONV (OFF_MS + NB*NF)

typedef unsigned long long u64;

__device__ __forceinline__ u64 rotl64v(u64 x, int r) {
    r &= 63;
    return r ? ((x << r) | (x >> (64 - r))) : x;
}

// Pack codebooks (f,v,d) +-1 floats into two bit layouts in d_ws:
//  cbB[(j*32+w)*64 + v] : row bits, bit l = sign of cb[j,v,w*64+l]
//  cbT[j*2048 + d]      : column mask, bit v = sign of cb[j,v,d]
__global__ void pack_cb_kernel(const float* __restrict__ cb,
                               u64* __restrict__ cbB, u64* __restrict__ cbT) {
    const int lane = threadIdx.x & 63;
    const int gw   = (blockIdx.x * (blockDim.x >> 6)) + (threadIdx.x >> 6);
    const int nw   = (gridDim.x * blockDim.x) >> 6;
    for (int idx = gw; idx < NF * NV * NW; idx += nw) {
        const int j = idx >> 11, v = (idx >> 5) & 63, w = idx & 31;
        const float x = cb[(((j << 6) | v) << 11) + (w << 6) + lane];
        const u64 m = __ballot(x < 0.0f);
        if (lane == 0) cbB[(((j << 5) | w) << 6) | v] = m;
    }
    for (int idx = gw; idx < NF * ND; idx += nw) {
        const int j = idx >> 11, d = idx & 2047;
        const float x = cb[(((j << 6) | lane) << 11) + d];
        const u64 m = __ballot(x < 0.0f);
        if (lane == 0) cbT[idx] = m;
    }
}

__global__ __launch_bounds__(256, 3) void resonator_kernel(
    const float* __restrict__ inp, const float* __restrict__ est_init,
    const u64* __restrict__ cbB, const u64* __restrict__ cbT,
    float* __restrict__ out) {
    __shared__ u64 s_hist[RING][NF][NW];   // est ring, 16 KB
    __shared__ u64 s_inp[NW];
    __shared__ u64 s_ne[NF][NW];           // per-factor ne, 1 KB
    __shared__ u64 s_hp[NF][2];            // per-wave partial hash
    __shared__ u64 s_hring[RING][2];       // combined 128b hash ring
    __shared__ int s_ok[NF];

    const int b    = blockIdx.x;
    const int tid  = threadIdx.x;
    const int j    = tid >> 6;      // wave = factor
    const int lane = tid & 63;

    const u64* cbBj = cbB + (j << 11);
    const u64* cbTj = cbT + (j << 11);

    // ---- static per-lane data: cbT columns in registers + packed colb ----
    u64 col[NW];
    uint32_t colbp[8];
    #pragma unroll
    for (int w = 0; w < 8; ++w) colbp[w] = 0u;
    #pragma unroll
    for (int w = 0; w < NW; ++w) {
        col[w] = cbTj[(w << 6) + lane];
        colbp[w >> 2] |= ((uint32_t)__popcll(col[w])) << ((w & 3) * 8);
    }

    // ---- pack input (8 words/wave) + est_0 (own factor) with hash ----
    {
        #pragma unroll
        for (int k = 0; k < 8; ++k) {
            const int w = (j << 3) + k;
            const float x = inp[(b << 11) + (w << 6) + lane];
            const u64 m = __ballot(x < 0.0f);
            if (lane == 0) s_inp[w] = m;
        }
        u64 hx = 0, ha = 0;
        #pragma unroll 4
        for (int w = 0; w < NW; ++w) {
            const float x = est_init[(((b << 2) | j) << 11) + (w << 6) + lane];
            const u64 m = __ballot(x < 0.0f);
            if (lane == 0) s_hist[0][j][w] = m;
            const u64 rm = rotl64v(m, (((j << 5) | w) * 11) & 63);
            hx ^= rm; ha += rm;
        }
        if (lane == 0) { s_hp[j][0] = hx; s_hp[j][1] = ha; }
    }
    __syncthreads();
    if (tid == 0) {
        s_hring[0][0] = s_hp[0][0] ^ s_hp[1][0] ^ s_hp[2][0] ^ s_hp[3][0];
        s_hring[0][1] = s_hp[0][1] + s_hp[1][1] + s_hp[2][1] + s_hp[3][1];
    }

    int brk_p = 0, brk_anti = 0, brk_it = ITERS;

    for (int it = 0; it < ITERS; ++it) {
        const int cur = it & 15, nxt = (it + 1) & 15;

        // (a) ne per factor (waves 0,1)
        if (tid < 128) {
            const int jj = tid >> 5, w = tid & 31;
            const u64 X = s_inp[w] ^ s_hist[cur][0][w] ^ s_hist[cur][1][w]
                                   ^ s_hist[cur][2][w] ^ s_hist[cur][3][w];
            s_ne[jj][w] = X ^ s_hist[cur][jj][w];
        }
        __syncthreads();                                  // B1

        // (b) phase B: pc_v; lane = v
        int pc = 0;
        #pragma unroll
        for (int w = 0; w < NW; ++w)
            pc += (int)__popcll(s_ne[j][w] ^ cbBj[(w << 6) | lane]);

        int mn = pc, mx = pc, spc = pc;
        #pragma unroll
        for (int off = 32; off > 0; off >>= 1) {
            const int a1 = __shfl_xor(mn, off);
            const int a2 = __shfl_xor(mx, off);
            const int a3 = __shfl_xor(spc, off);
            mn = mn < a1 ? mn : a1;
            mx = mx > a2 ? mx : a2;
            spc += a3;
        }
        const int q = pc - mn;
        const int R = mx - mn;
        const int P = R ? (32 - __clz(R)) : 0;
        const int base = 131072 - 2 * spc;
        const int cmul = 4 * mn - 4096;

        // phase C: D_d = base + cmul*colb_d + 4*sum_v q_v b_vd; lane = d%64
        int D[NW];
        #pragma unroll
        for (int w = 0; w < NW; ++w) {
            const int colb = (int)((colbp[w >> 2] >> ((w & 3) * 8)) & 255u);
            D[w] = base + cmul * colb;
        }
        for (int k = 0; k < P; ++k) {
            const u64 ck = __ballot((q >> k) & 1);
            #pragma unroll
            for (int w = 0; w < NW; ++w)
                D[w] += (int)__popcll(ck & col[w]) << (k + 2);
        }
        u64 phx = 0, pha = 0;
        #pragma unroll
        for (int w = 0; w < NW; ++w) {
            const u64 nww = __ballot(D[w] < 0);
            if (lane == 0) s_hist[nxt][j][w] = nww;
            const u64 rm = rotl64v(nww, (((j << 5) | w) * 11) & 63);
            phx ^= rm; pha += rm;
        }
        if (lane == 0) { s_hp[j][0] = phx; s_hp[j][1] = pha; }
        __syncthreads();                                  // B2

        // (c) combine hash, ring compare (identical in every wave -> uniform)
        const u64 HX = s_hp[0][0] ^ s_hp[1][0] ^ s_hp[2][0] ^ s_hp[3][0];
        const u64 HA = s_hp[0][1] + s_hp[1][1] + s_hp[2][1] + s_hp[3][1];
        if (tid == 0) { s_hring[nxt][0] = HX; s_hring[nxt][1] = HA; }
        const u64 HAa = (u64)0 - 128ull - HA;   // hash of complemented state
        int mask = 0;
        const int pmax = (it + 1) < (RING - 1) ? (it + 1) : (RING - 1);
        for (int p = 1; p <= pmax; ++p) {
            const u64 rx = s_hring[(it + 1 - p) & 15][0];
            const u64 ra = s_hring[(it + 1 - p) & 15][1];
            if (rx == HX && ra == HA)  mask |= (1 << p);
            if (rx == HX && ra == HAa) mask |= (1 << (p + 16));
        }

        if (mask) {
            int fp = 0, fa = 0;
            for (int p = 1; p <= pmax && !fp; ++p) {
                for (int a2 = 0; a2 < 2 && !fp; ++a2) {
                    if (!(mask & (1 << (p + (a2 ? 16 : 0))))) continue;
                    int okl = 1;
                    if (lane < NW) {
                        const u64 wa = s_hist[nxt][j][lane];
                        u64 wb = s_hist[(it + 1 - p) & 15][j][lane];
                        if (a2) wb = ~wb;
                        okl = (wa == wb);
                    }
                    const u64 bal = __ballot(okl != 0);
                    if (lane == 0) s_ok[j] = (bal == ~0ull);
                    __syncthreads();
                    const int allok = s_ok[0] & s_ok[1] & s_ok[2] & s_ok[3];
                    __syncthreads();
                    if (allok) { fp = p; fa = a2; }
                }
            }
            if (fp) { brk_p = fp; brk_anti = fa; brk_it = it; break; }
        }
    }

    // ---- map iterations 99/100 into the ring (orbit-aware, exact) ----
    int slot100, comp100, slot99, comp99;
    if (brk_p) {
        const int s0 = brk_it + 1 - brk_p;
        const int r1 = (ITERS - s0) % brk_p;
        const int c1 = s0 + r1, t1 = (ITERS - c1) / brk_p;
        const int r2 = (ITERS - 1 - s0) % brk_p;
        const int c2 = s0 + r2, t2 = (ITERS - 1 - c2) / brk_p;
        slot100 = c1 & 15; comp100 = brk_anti & (t1 & 1);
        slot99  = c2 & 15; comp99  = brk_anti & (t2 & 1);
    } else {
        slot100 = ITERS & 15;       comp100 = 0;
        slot99  = (ITERS - 1) & 15; comp99  = 0;
    }
    __syncthreads();

    // ---- max_sims[-1] = 2048 - 2*min_v pc on ne(est_99) ----
    int pc9 = 0;
    #pragma unroll
    for (int w = 0; w < NW; ++w) {
        const u64 X = s_inp[w] ^ s_hist[slot99][0][w] ^ s_hist[slot99][1][w]
                               ^ s_hist[slot99][2][w] ^ s_hist[slot99][3][w];
        const u64 ne = X ^ s_hist[slot99][j][w];
        pc9 += (int)__popcll(ne ^ cbBj[(w << 6) | lane]);
    }
    if (comp99) pc9 = ND - pc9;
    int m9 = pc9;
    #pragma unroll
    for (int off = 32; off > 0; off >>= 1) {
        const int a1 = __shfl_xor(m9, off);
        m9 = m9 < a1 ? m9 : a1;
    }

    // ---- outcome: argmax_v |sim(est_100, cb)| (|.| is comp-invariant) ----
    int pcO = 0;
    #pragma unroll
    for (int w = 0; w < NW; ++w)
        pcO += (int)__popcll(s_hist[slot100][j][w] ^ cbBj[(w << 6) | lane]);
    const int simF = ND - (pcO << 1);
    const int aF   = simF < 0 ? -simF : simF;
    int key = (aF << 6) | (63 - lane);
    #pragma unroll
    for (int off = 32; off > 0; off >>= 1) {
        const int t1 = __shfl_xor(key, off);
        key = key > t1 ? key : t1;
    }
    const int vstar = 63 - (key & 63);
    if (lane == 0) {
        out[OFF_OUT + (b << 2) + j] = (float)vstar;
        out[OFF_MS  + (b << 2) + j] = (float)(ND - 2 * m9);
    }

    // ---- unpack est_100 ----
    const u64 cmask = comp100 ? ~0ull : 0ull;
    #pragma unroll 4
    for (int k = 0; k < 32; ++k) {
        const int idx = tid + (k << 8);        // 0..8191
        const int jj = idx >> 11, d = idx & 2047;
        const u64 wrd = s_hist[slot100][jj][d >> 6] ^ cmask;
        out[(b << 13) + idx] = ((wrd >> (d & 63)) & 1) ? -1.0f : 1.0f;
    }
    if (b == 0 && tid == 0) out[OFF_CONV] = 99.0f;
}

extern "C" void kernel_launch(void* const* d_in, const int* in_sizes, int n_in,
                              void* d_out, int out_size, void* d_ws, size_t ws_size,
                              hipStream_t stream) {
    const float* inp  = (const float*)d_in[0];
    const float* est0 = (const float*)d_in[1];
    const float* cb   = (const float*)d_in[2];
    float* out = (float*)d_out;
    u64* cbB = (u64*)d_ws;                 // 8192 words
    u64* cbT = cbB + NF * NV * NW;         // 8192 words (128 KB of ws total)

    pack_cb_kernel<<<64, 256, 0, stream>>>(cb, cbB, cbT);
    resonator_kernel<<<NB, 256, 0, stream>>>(inp, est0, cbB, cbT, out);
}